// Round 4
// baseline (365.032 us; speedup 1.0000x reference)
//
#include <hip/hip_runtime.h>
#include <cstddef>

#define D_FEAT 64
#define S_DIM 16
#define H_DIM 32
#define OUT_DIM 16
#define MAX_IT 5

typedef _Float16 half8 __attribute__((ext_vector_type(8)));

__device__ __forceinline__ float fast_tanh(float x) {
    float xc = fminf(fmaxf(x, -15.0f), 15.0f);
    float e = __expf(2.0f * xc);
    return (e - 1.0f) / (e + 1.0f);
}

// ---- CSR construction (counting sort by src) ----
__global__ __launch_bounds__(256)
void k_hist(const int* __restrict__ src, int* __restrict__ deg, int E) {
    int e = blockIdx.x * 256 + threadIdx.x;
    if (e < E) atomicAdd(&deg[src[e]], 1);
}

__global__ __launch_bounds__(1024)
void k_scan(const int* __restrict__ deg, int* __restrict__ cursor, int N) {
    __shared__ int wsum[16];
    __shared__ int carry;
    int lane = threadIdx.x & 63;
    int wid = threadIdx.x >> 6;
    if (threadIdx.x == 0) carry = 0;
    __syncthreads();
    for (int base = 0; base < N; base += 1024) {
        int i = base + (int)threadIdx.x;
        int v = (i < N) ? deg[i] : 0;
        int incl = v;
#pragma unroll
        for (int off = 1; off < 64; off <<= 1) {
            int t = __shfl_up(incl, off, 64);
            if (lane >= off) incl += t;
        }
        if (lane == 63) wsum[wid] = incl;
        __syncthreads();
        if (wid == 0) {
            int w = (lane < 16) ? wsum[lane] : 0;
            int wi = w;
#pragma unroll
            for (int off = 1; off < 16; off <<= 1) {
                int t = __shfl_up(wi, off, 64);
                if (lane >= off) wi += t;
            }
            if (lane < 16) wsum[lane] = wi - w;
        }
        __syncthreads();
        int excl = incl - v + wsum[wid] + carry;
        if (i < N) cursor[i] = excl;
        __syncthreads();
        if ((int)threadIdx.x == 1023) carry = excl + v;
        __syncthreads();
    }
}

__global__ __launch_bounds__(256)
void k_scatter(const int* __restrict__ src, const int* __restrict__ dst,
               int* __restrict__ cursor, int* __restrict__ pos,
               int* __restrict__ dstp, int* __restrict__ srcp, int E) {
    int e = blockIdx.x * 256 + threadIdx.x;
    if (e >= E) return;
    int s = src[e];
    int p = atomicAdd(&cursor[s], 1);
    pos[e] = p;
    dstp[p] = dst[e];
    srcp[p] = s;
}

// pre[pos[e]] = fp16(bst1 + feat[e] @ Wst1[:64])
// LDS-staged: 2 passes of 32 cols x 256 rows (32KB), coalesced float4 global loads,
// dword-swizzled LDS layout for conflict-free compute reads. Math order identical
// to the direct version (k ascending, j inner) -> bit-identical output.
__global__ __launch_bounds__(256)
void k_pre(const float* __restrict__ feat, const float* __restrict__ Wst1,
           const float* __restrict__ bst1, const int* __restrict__ pos,
           _Float16* __restrict__ pre, int E) {
    __shared__ float sfeat[256 * 32];
    const int t = threadIdx.x;
    const int base = blockIdx.x * 256;
    const int e = base + t;
    const bool valid = e < E;
    float acc[H_DIM];
#pragma unroll
    for (int j = 0; j < H_DIM; ++j) acc[j] = bst1[j];

#pragma unroll
    for (int p = 0; p < 2; ++p) {
        // stage cols [32p, 32p+32) of rows [base, base+256)
#pragma unroll
        for (int i = 0; i < 8; ++i) {
            int idx4 = t + i * 256;         // 0..2047 float4s
            int r = idx4 >> 3;              // row 0..255
            int c0 = (idx4 & 7) * 4;        // dword col within 32-col half
            if (base + r < E) {
                const float4 v = *reinterpret_cast<const float4*>(
                    feat + (size_t)(base + r) * D_FEAT + p * 32 + c0);
                sfeat[r * 32 + ((c0 + 0 + r) & 31)] = v.x;
                sfeat[r * 32 + ((c0 + 1 + r) & 31)] = v.y;
                sfeat[r * 32 + ((c0 + 2 + r) & 31)] = v.z;
                sfeat[r * 32 + ((c0 + 3 + r) & 31)] = v.w;
            }
        }
        __syncthreads();
        if (valid) {
            const float* wbase = Wst1 + (size_t)p * 32 * H_DIM;
#pragma unroll
            for (int k = 0; k < 32; ++k) {
                float v = sfeat[t * 32 + ((k + t) & 31)];
                const float* w = wbase + k * H_DIM;  // wave-uniform -> s_load
#pragma unroll
                for (int j = 0; j < H_DIM; ++j) acc[j] = fmaf(v, w[j], acc[j]);
            }
        }
        __syncthreads();
    }
    if (!valid) return;
    int p16 = pos[e];
    half8* op = reinterpret_cast<half8*>(pre + (size_t)p16 * H_DIM);
#pragma unroll
    for (int j8 = 0; j8 < 4; ++j8) {
        half8 v;
#pragma unroll
        for (int kk = 0; kk < 8; ++kk) v[kk] = (_Float16)acc[j8 * 8 + kk];
        op[j8] = v;
    }
}

// Fused: LDS-staged pre + edge MLP + in-block segmented sum -> new_state
__global__ __launch_bounds__(256)
void k_edge(const _Float16* __restrict__ pre, const float* __restrict__ nodeH,
            const int* __restrict__ dstp, const int* __restrict__ srcp,
            const float* __restrict__ Wst2, const float* __restrict__ bst2,
            float* __restrict__ new_state, const int* __restrict__ flags,
            int it, int E) {
#pragma unroll
    for (int j = 0; j < MAX_IT; ++j)
        if (j < it && flags[2 + j] == 0) return;  // converged earlier -> frozen
    __shared__ float spre[256 * 16];  // raw fp16-pair dwords, swizzled in 16-dword rows
    __shared__ float sres[256][20];
    __shared__ int ssrc[256];
    const int t = threadIdx.x;
    const int base = blockIdx.x * 256;
    const int ep = base + t;
    const bool valid = ep < E;

    // coalesced stage of this block's 16KB of pre
    const int navail4 = (E - base) * 4;  // float4s available
    const float4* psrc = reinterpret_cast<const float4*>(pre + (size_t)base * H_DIM);
#pragma unroll
    for (int i = 0; i < 4; ++i) {
        int idx4 = t + i * 256;
        if (idx4 < navail4) {
            float4 v = psrc[idx4];
            int r = idx4 >> 2;
            int c0 = (idx4 & 3) * 4;
            spre[r * 16 + ((c0 + 0 + r) & 15)] = v.x;
            spre[r * 16 + ((c0 + 1 + r) & 15)] = v.y;
            spre[r * 16 + ((c0 + 2 + r) & 15)] = v.z;
            spre[r * 16 + ((c0 + 3 + r) & 15)] = v.w;
        }
    }
    int s = valid ? srcp[ep] : (int)0x80000000;
    ssrc[t] = s;
    int d = valid ? dstp[ep] : 0;
    __syncthreads();

    float res[S_DIM];
    if (valid) {
        const float4* hp = reinterpret_cast<const float4*>(nodeH + (size_t)d * H_DIM);
        float h[H_DIM];
#pragma unroll
        for (int q = 0; q < 8; ++q) {
            float4 a = hp[q];
            union { float f; _Float16 hh[2]; } c0v, c1v;
            c0v.f = spre[t * 16 + ((2 * q + 0 + t) & 15)];
            c1v.f = spre[t * 16 + ((2 * q + 1 + t) & 15)];
            h[4 * q + 0] = fast_tanh((float)c0v.hh[0] + a.x);
            h[4 * q + 1] = fast_tanh((float)c0v.hh[1] + a.y);
            h[4 * q + 2] = fast_tanh((float)c1v.hh[0] + a.z);
            h[4 * q + 3] = fast_tanh((float)c1v.hh[1] + a.w);
        }
        float r[S_DIM];
#pragma unroll
        for (int i = 0; i < S_DIM; ++i) r[i] = bst2[i];
#pragma unroll
        for (int j = 0; j < H_DIM; ++j) {
            const float* w = Wst2 + (size_t)j * S_DIM;  // wave-uniform -> s_load
            float hj = h[j];
#pragma unroll
            for (int i = 0; i < S_DIM; ++i) r[i] = fmaf(hj, w[i], r[i]);
        }
#pragma unroll
        for (int i = 0; i < S_DIM; ++i) {
            res[i] = fast_tanh(r[i]);
            sres[t][i] = res[i];
        }
    }
    __syncthreads();
    if (!valid) return;
    bool local_head = (t == 0) || (ssrc[t - 1] != s);
    if (!local_head) return;
    float acc[S_DIM];
#pragma unroll
    for (int i = 0; i < S_DIM; ++i) acc[i] = res[i];
    int t2 = t + 1;
    while (t2 < 256 && base + t2 < E && ssrc[t2] == s) {
        const float4* rp = reinterpret_cast<const float4*>(&sres[t2][0]);
        float4 a0 = rp[0], a1 = rp[1], a2 = rp[2], a3 = rp[3];
        acc[0] += a0.x; acc[1] += a0.y; acc[2] += a0.z; acc[3] += a0.w;
        acc[4] += a1.x; acc[5] += a1.y; acc[6] += a1.z; acc[7] += a1.w;
        acc[8] += a2.x; acc[9] += a2.y; acc[10] += a2.z; acc[11] += a2.w;
        acc[12] += a3.x; acc[13] += a3.y; acc[14] += a3.z; acc[15] += a3.w;
        ++t2;
    }
    bool trueStart = (t > 0) || (ep == 0) || (srcp[ep - 1] != s);
    int ge = base + t2;
    bool trueEnd = (t2 < 256) || (ge >= E) || (srcp[ge] != s);
    float* ns = new_state + (size_t)s * S_DIM;
    if (trueStart && trueEnd) {
        float4* nsp = reinterpret_cast<float4*>(ns);
        nsp[0] = make_float4(acc[0], acc[1], acc[2], acc[3]);
        nsp[1] = make_float4(acc[4], acc[5], acc[6], acc[7]);
        nsp[2] = make_float4(acc[8], acc[9], acc[10], acc[11]);
        nsp[3] = make_float4(acc[12], acc[13], acc[14], acc[15]);
    } else {
#pragma unroll
        for (int i = 0; i < S_DIM; ++i) atomicAdd(ns + i, acc[i]);
    }
}

// 4 threads/node: convergence, state <- new_state, new_state <- 0, nodeH = state@Wst1[64:]
__global__ __launch_bounds__(256)
void k_node(float* __restrict__ state, float* __restrict__ new_state,
            float* __restrict__ nodeH, const float* __restrict__ Wst1,
            int* __restrict__ flags, int it, int N) {
#pragma unroll
    for (int j = 0; j < MAX_IT; ++j)
        if (j < it && flags[2 + j] == 0) return;
    int tt = blockIdx.x * 256 + threadIdx.x;
    int n = tt >> 2;
    int q = tt & 3;
    if (n >= N) return;
    float4* nsp = reinterpret_cast<float4*>(new_state + (size_t)n * S_DIM);
    float4* sp = reinterpret_cast<float4*>(state + (size_t)n * S_DIM);
    float4 acc = nsp[q];
    float4 old = sp[q];
    float dx = acc.x - old.x, dy = acc.y - old.y, dz = acc.z - old.z, dw = acc.w - old.w;
    float d2 = dx * dx + dy * dy + dz * dz + dw * dw;
    sp[q] = acc;
    nsp[q] = make_float4(0.f, 0.f, 0.f, 0.f);
    d2 += __shfl_xor(d2, 1);
    d2 += __shfl_xor(d2, 2);
    if (q == 0 && d2 + 1e-10f > 1e-4f) flags[2 + it] = 1;  // benign racy store of 1

    float st[S_DIM];
    st[q * 4 + 0] = acc.x; st[q * 4 + 1] = acc.y; st[q * 4 + 2] = acc.z; st[q * 4 + 3] = acc.w;
#pragma unroll
    for (int m = 1; m < 4; ++m) {
        int qs = q ^ m;
        st[qs * 4 + 0] = __shfl_xor(acc.x, m);
        st[qs * 4 + 1] = __shfl_xor(acc.y, m);
        st[qs * 4 + 2] = __shfl_xor(acc.z, m);
        st[qs * 4 + 3] = __shfl_xor(acc.w, m);
    }
    float hh[8];
#pragma unroll
    for (int j = 0; j < 8; ++j) hh[j] = 0.f;
#pragma unroll
    for (int k = 0; k < S_DIM; ++k) {
        const float* w = Wst1 + (size_t)(D_FEAT + k) * H_DIM + q * 8;
        float sk = st[k];
#pragma unroll
        for (int j = 0; j < 8; ++j) hh[j] = fmaf(sk, w[j], hh[j]);
    }
    float4* hp = reinterpret_cast<float4*>(nodeH + (size_t)n * H_DIM + q * 8);
    hp[0] = make_float4(hh[0], hh[1], hh[2], hh[3]);
    hp[1] = make_float4(hh[4], hh[5], hh[6], hh[7]);
}

__global__ __launch_bounds__(256)
void gnn_out(const float* __restrict__ state, const float* __restrict__ Wout1,
             const float* __restrict__ bout1, const float* __restrict__ Wout2,
             const float* __restrict__ bout2, float* __restrict__ out, int N) {
    int n = blockIdx.x * 256 + threadIdx.x;
    if (n >= N) return;
    float st[S_DIM];
    const float4* sp = reinterpret_cast<const float4*>(state + (size_t)n * S_DIM);
    float4 v0 = sp[0], v1 = sp[1], v2 = sp[2], v3 = sp[3];
    st[0] = v0.x; st[1] = v0.y; st[2] = v0.z; st[3] = v0.w;
    st[4] = v1.x; st[5] = v1.y; st[6] = v1.z; st[7] = v1.w;
    st[8] = v2.x; st[9] = v2.y; st[10] = v2.z; st[11] = v2.w;
    st[12] = v3.x; st[13] = v3.y; st[14] = v3.z; st[15] = v3.w;

    float h[H_DIM];
#pragma unroll
    for (int j = 0; j < H_DIM; ++j) {
        float acc = bout1[j];
#pragma unroll
        for (int k = 0; k < S_DIM; ++k) acc = fmaf(st[k], Wout1[(size_t)k * H_DIM + j], acc);
        h[j] = fast_tanh(acc);
    }
    float l[OUT_DIM];
#pragma unroll
    for (int i = 0; i < OUT_DIM; ++i) l[i] = bout2[i];
#pragma unroll
    for (int j = 0; j < H_DIM; ++j) {
        float hj = h[j];
#pragma unroll
        for (int i = 0; i < OUT_DIM; ++i) l[i] = fmaf(hj, Wout2[(size_t)j * OUT_DIM + i], l[i]);
    }
    float m = l[0];
#pragma unroll
    for (int i = 1; i < OUT_DIM; ++i) m = fmaxf(m, l[i]);
    float sum = 0.0f;
#pragma unroll
    for (int i = 0; i < OUT_DIM; ++i) {
        float tv = __expf(l[i] - m);
        l[i] = tv;
        sum += tv;
    }
    float inv = 1.0f / sum;
    float4* op = reinterpret_cast<float4*>(out + (size_t)n * OUT_DIM);
    op[0] = make_float4(l[0] * inv, l[1] * inv, l[2] * inv, l[3] * inv);
    op[1] = make_float4(l[4] * inv, l[5] * inv, l[6] * inv, l[7] * inv);
    op[2] = make_float4(l[8] * inv, l[9] * inv, l[10] * inv, l[11] * inv);
    op[3] = make_float4(l[12] * inv, l[13] * inv, l[14] * inv, l[15] * inv);
}

extern "C" void kernel_launch(void* const* d_in, const int* in_sizes, int n_in,
                              void* d_out, int out_size, void* d_ws, size_t ws_size,
                              hipStream_t stream) {
    const float* edge_feat = (const float*)d_in[0];
    const float* Wst1 = (const float*)d_in[1];
    const float* bst1 = (const float*)d_in[2];
    const float* Wst2 = (const float*)d_in[3];
    const float* bst2 = (const float*)d_in[4];
    const float* Wout1 = (const float*)d_in[5];
    const float* bout1 = (const float*)d_in[6];
    const float* Wout2 = (const float*)d_in[7];
    const float* bout2 = (const float*)d_in[8];
    const int* esrc = (const int*)d_in[9];
    const int* edst = (const int*)d_in[10];
    const int E = in_sizes[9];
    const int N = out_size / OUT_DIM;
    float* out = (float*)d_out;

    // ws layout (floats): state[N*16] | nodeH[N*32] | new_state[N*16] |
    // pre (_Float16, E*32) | pos[E] | dstp[E] | srcp[E] | deg[N] | cursor[N] | flags[8]
    float* state = (float*)d_ws;
    float* nodeH = state + (size_t)N * S_DIM;
    float* new_state = nodeH + (size_t)N * H_DIM;
    _Float16* pre = (_Float16*)(new_state + (size_t)N * S_DIM);
    int* pos = (int*)(pre + (size_t)E * H_DIM);
    int* dstp = pos + E;
    int* srcp = dstp + E;
    int* deg = srcp + E;
    int* cursor = deg + N;
    int* flags = cursor + N;

    hipMemsetAsync(state, 0, (size_t)N * (S_DIM + H_DIM + S_DIM) * sizeof(float), stream);
    hipMemsetAsync(deg, 0, (size_t)N * sizeof(int), stream);
    hipMemsetAsync(flags, 0, 8 * sizeof(int), stream);

    int ebl = (E + 255) / 256;
    int nbl = (N + 255) / 256;
    int rbl = (N * 4 + 255) / 256;

    k_hist<<<ebl, 256, 0, stream>>>(esrc, deg, E);
    k_scan<<<1, 1024, 0, stream>>>(deg, cursor, N);
    k_scatter<<<ebl, 256, 0, stream>>>(esrc, edst, cursor, pos, dstp, srcp, E);
    k_pre<<<ebl, 256, 0, stream>>>(edge_feat, Wst1, bst1, pos, pre, E);

    for (int it = 0; it < MAX_IT; ++it) {
        k_edge<<<ebl, 256, 0, stream>>>(pre, nodeH, dstp, srcp, Wst2, bst2,
                                        new_state, flags, it, E);
        k_node<<<rbl, 256, 0, stream>>>(state, new_state, nodeH, Wst1, flags, it, N);
    }
    gnn_out<<<nbl, 256, 0, stream>>>(state, Wout1, bout1, Wout2, bout2, out, N);
}

// Round 5
// 304.068 us; speedup vs baseline: 1.2005x; 1.2005x over previous
//
#include <hip/hip_runtime.h>
#include <cstddef>

#define D_FEAT 64
#define S_DIM 16
#define H_DIM 32
#define OUT_DIM 16
#define MAX_IT 5

typedef _Float16 half8 __attribute__((ext_vector_type(8)));

__device__ __forceinline__ float fast_tanh(float x) {
    float xc = fminf(fmaxf(x, -15.0f), 15.0f);
    float e = __expf(2.0f * xc);
    return (e - 1.0f) / (e + 1.0f);
}

// ---- CSR construction (counting sort by src) ----
__global__ __launch_bounds__(256)
void k_hist(const int* __restrict__ src, int* __restrict__ deg, int E) {
    int e = blockIdx.x * 256 + threadIdx.x;
    if (e < E) atomicAdd(&deg[src[e]], 1);
}

__global__ __launch_bounds__(1024)
void k_scan(const int* __restrict__ deg, int* __restrict__ cursor, int N) {
    __shared__ int wsum[16];
    __shared__ int carry;
    int lane = threadIdx.x & 63;
    int wid = threadIdx.x >> 6;
    if (threadIdx.x == 0) carry = 0;
    __syncthreads();
    for (int base = 0; base < N; base += 1024) {
        int i = base + (int)threadIdx.x;
        int v = (i < N) ? deg[i] : 0;
        int incl = v;
#pragma unroll
        for (int off = 1; off < 64; off <<= 1) {
            int t = __shfl_up(incl, off, 64);
            if (lane >= off) incl += t;
        }
        if (lane == 63) wsum[wid] = incl;
        __syncthreads();
        if (wid == 0) {
            int w = (lane < 16) ? wsum[lane] : 0;
            int wi = w;
#pragma unroll
            for (int off = 1; off < 16; off <<= 1) {
                int t = __shfl_up(wi, off, 64);
                if (lane >= off) wi += t;
            }
            if (lane < 16) wsum[lane] = wi - w;
        }
        __syncthreads();
        int excl = incl - v + wsum[wid] + carry;
        if (i < N) cursor[i] = excl;
        __syncthreads();
        if ((int)threadIdx.x == 1023) carry = excl + v;
        __syncthreads();
    }
}

__global__ __launch_bounds__(256)
void k_scatter(const int* __restrict__ src, const int* __restrict__ dst,
               int* __restrict__ cursor, int* __restrict__ pos,
               int* __restrict__ dstp, int* __restrict__ srcp, int E) {
    int e = blockIdx.x * 256 + threadIdx.x;
    if (e >= E) return;
    int s = src[e];
    int p = atomicAdd(&cursor[s], 1);
    pos[e] = p;
    dstp[p] = dst[e];
    srcp[p] = s;
}

// pre[pos[e]] = fp16(bst1 + feat[e] @ Wst1[:64]) — direct per-thread row reads
// (round-3 version: latency hidden by high occupancy; LDS staging regressed it)
__global__ __launch_bounds__(256)
void k_pre(const float* __restrict__ feat, const float* __restrict__ Wst1,
           const float* __restrict__ bst1, const int* __restrict__ pos,
           _Float16* __restrict__ pre, int E) {
    int e = blockIdx.x * 256 + threadIdx.x;
    if (e >= E) return;
    float acc[H_DIM];
#pragma unroll
    for (int j = 0; j < H_DIM; ++j) acc[j] = bst1[j];
    const float4* f4 = reinterpret_cast<const float4*>(feat + (size_t)e * D_FEAT);
#pragma unroll 4
    for (int k4 = 0; k4 < D_FEAT / 4; ++k4) {
        float4 v = f4[k4];
        const float* w = Wst1 + k4 * 4 * H_DIM;
#pragma unroll
        for (int j = 0; j < H_DIM; ++j) acc[j] = fmaf(v.x, w[j], acc[j]);
#pragma unroll
        for (int j = 0; j < H_DIM; ++j) acc[j] = fmaf(v.y, w[H_DIM + j], acc[j]);
#pragma unroll
        for (int j = 0; j < H_DIM; ++j) acc[j] = fmaf(v.z, w[2 * H_DIM + j], acc[j]);
#pragma unroll
        for (int j = 0; j < H_DIM; ++j) acc[j] = fmaf(v.w, w[3 * H_DIM + j], acc[j]);
    }
    int p = pos[e];
    half8* op = reinterpret_cast<half8*>(pre + (size_t)p * H_DIM);
#pragma unroll
    for (int j8 = 0; j8 < 4; ++j8) {
        half8 v;
#pragma unroll
        for (int k = 0; k < 8; ++k) v[k] = (_Float16)acc[j8 * 8 + k];
        op[j8] = v;
    }
}

// Fused: edge MLP + PARALLEL in-block segmented sum -> new_state.
// Segment extents via per-wave shuffle min-scan of tail markers (no serial walk);
// reduction done by nseg*16 workers (one per segment x dim), coalesced stores.
__global__ __launch_bounds__(256)
void k_edge(const _Float16* __restrict__ pre, const float* __restrict__ nodeH,
            const int* __restrict__ dstp, const int* __restrict__ srcp,
            const float* __restrict__ Wst2, const float* __restrict__ bst2,
            float* __restrict__ new_state, const int* __restrict__ flags,
            int it, int E) {
#pragma unroll
    for (int j = 0; j < MAX_IT; ++j)
        if (j < it && flags[2 + j] == 0) return;  // converged earlier -> frozen
    __shared__ float sres[256][17];   // stride 17: worker column reads cycle banks
    __shared__ int ssrc[256];
    __shared__ int send[256];
    __shared__ int segs[256];
    __shared__ int wf[4];
    __shared__ int nseg;
    const int t = threadIdx.x;
    const int lane = t & 63;
    const int wid = t >> 6;
    const int base = blockIdx.x * 256;
    const int ep = base + t;
    const bool valid = ep < E;
    if (t == 0) nseg = 0;

    int s = valid ? srcp[ep] : (int)0x80000000;  // sentinel segment at tail
    ssrc[t] = s;

    if (valid) {
        int d = dstp[ep];
        const half8* pp = reinterpret_cast<const half8*>(pre + (size_t)ep * H_DIM);
        const float4* hp = reinterpret_cast<const float4*>(nodeH + (size_t)d * H_DIM);
        float h[H_DIM];
#pragma unroll
        for (int j8 = 0; j8 < 4; ++j8) {
            half8 pv = pp[j8];
            float4 a = hp[j8 * 2], b = hp[j8 * 2 + 1];
            h[j8 * 8 + 0] = fast_tanh((float)pv[0] + a.x);
            h[j8 * 8 + 1] = fast_tanh((float)pv[1] + a.y);
            h[j8 * 8 + 2] = fast_tanh((float)pv[2] + a.z);
            h[j8 * 8 + 3] = fast_tanh((float)pv[3] + a.w);
            h[j8 * 8 + 4] = fast_tanh((float)pv[4] + b.x);
            h[j8 * 8 + 5] = fast_tanh((float)pv[5] + b.y);
            h[j8 * 8 + 6] = fast_tanh((float)pv[6] + b.z);
            h[j8 * 8 + 7] = fast_tanh((float)pv[7] + b.w);
        }
        float r[S_DIM];
#pragma unroll
        for (int i = 0; i < S_DIM; ++i) r[i] = bst2[i];
#pragma unroll
        for (int j = 0; j < H_DIM; ++j) {
            const float* w = Wst2 + (size_t)j * S_DIM;  // wave-uniform -> s_load
            float hj = h[j];
#pragma unroll
            for (int i = 0; i < S_DIM; ++i) r[i] = fmaf(hj, w[i], r[i]);
        }
#pragma unroll
        for (int i = 0; i < S_DIM; ++i) sres[t][i] = fast_tanh(r[i]);
    }
    __syncthreads();

    // segment heads/tails from sorted src
    bool head = (t == 0) || (ssrc[t - 1] != s);
    bool tail = (t == 255) || (ssrc[t + 1] != s);

    // per-wave inclusive min-scan (from the right) of tail positions -> segment end
    int mn = tail ? (t + 1) : 0x7fffffff;
#pragma unroll
    for (int off = 1; off < 64; off <<= 1) {
        int u = __shfl_down(mn, off, 64);
        if (lane + off < 64) mn = min(mn, u);
    }
    if (lane == 0) wf[wid] = mn;
    __syncthreads();
    int carry = 0x7fffffff;
#pragma unroll
    for (int w = 0; w < 4; ++w)
        if (w > wid) carry = min(carry, wf[w]);
    send[t] = min(mn, carry);
    int spos = -1;
    if (head && valid) spos = atomicAdd(&nseg, 1);
    if (spos >= 0) segs[spos] = t;
    __syncthreads();

    int ns = nseg;
    for (int w = t; w < ns * 16; w += 256) {
        int st = segs[w >> 4];
        int dim = w & 15;
        int en = send[st];
        int node = ssrc[st];
        float a = 0.f;
        for (int i = st; i < en; ++i) a += sres[i][dim];
        bool tS = (st > 0) || (base == 0) || (srcp[base - 1] != node);
        int gen = base + en;
        bool tE = (en < 256) || (gen >= E) || (srcp[gen] != node);
        float* p = new_state + (size_t)node * S_DIM + dim;
        if (tS && tE) *p = a;
        else atomicAdd(p, a);
    }
}

// 4 threads/node: convergence, state <- new_state, new_state <- 0, nodeH = state@Wst1[64:]
__global__ __launch_bounds__(256)
void k_node(float* __restrict__ state, float* __restrict__ new_state,
            float* __restrict__ nodeH, const float* __restrict__ Wst1,
            int* __restrict__ flags, int it, int N) {
#pragma unroll
    for (int j = 0; j < MAX_IT; ++j)
        if (j < it && flags[2 + j] == 0) return;
    int tt = blockIdx.x * 256 + threadIdx.x;
    int n = tt >> 2;
    int q = tt & 3;
    if (n >= N) return;
    float4* nsp = reinterpret_cast<float4*>(new_state + (size_t)n * S_DIM);
    float4* sp = reinterpret_cast<float4*>(state + (size_t)n * S_DIM);
    float4 acc = nsp[q];
    float4 old = sp[q];
    float dx = acc.x - old.x, dy = acc.y - old.y, dz = acc.z - old.z, dw = acc.w - old.w;
    float d2 = dx * dx + dy * dy + dz * dz + dw * dw;
    sp[q] = acc;
    nsp[q] = make_float4(0.f, 0.f, 0.f, 0.f);
    d2 += __shfl_xor(d2, 1);
    d2 += __shfl_xor(d2, 2);
    if (q == 0 && d2 + 1e-10f > 1e-4f) flags[2 + it] = 1;  // benign racy store of 1

    float st[S_DIM];
    st[q * 4 + 0] = acc.x; st[q * 4 + 1] = acc.y; st[q * 4 + 2] = acc.z; st[q * 4 + 3] = acc.w;
#pragma unroll
    for (int m = 1; m < 4; ++m) {
        int qs = q ^ m;
        st[qs * 4 + 0] = __shfl_xor(acc.x, m);
        st[qs * 4 + 1] = __shfl_xor(acc.y, m);
        st[qs * 4 + 2] = __shfl_xor(acc.z, m);
        st[qs * 4 + 3] = __shfl_xor(acc.w, m);
    }
    float hh[8];
#pragma unroll
    for (int j = 0; j < 8; ++j) hh[j] = 0.f;
#pragma unroll
    for (int k = 0; k < S_DIM; ++k) {
        const float* w = Wst1 + (size_t)(D_FEAT + k) * H_DIM + q * 8;
        float sk = st[k];
#pragma unroll
        for (int j = 0; j < 8; ++j) hh[j] = fmaf(sk, w[j], hh[j]);
    }
    float4* hp = reinterpret_cast<float4*>(nodeH + (size_t)n * H_DIM + q * 8);
    hp[0] = make_float4(hh[0], hh[1], hh[2], hh[3]);
    hp[1] = make_float4(hh[4], hh[5], hh[6], hh[7]);
}

__global__ __launch_bounds__(256)
void gnn_out(const float* __restrict__ state, const float* __restrict__ Wout1,
             const float* __restrict__ bout1, const float* __restrict__ Wout2,
             const float* __restrict__ bout2, float* __restrict__ out, int N) {
    int n = blockIdx.x * 256 + threadIdx.x;
    if (n >= N) return;
    float st[S_DIM];
    const float4* sp = reinterpret_cast<const float4*>(state + (size_t)n * S_DIM);
    float4 v0 = sp[0], v1 = sp[1], v2 = sp[2], v3 = sp[3];
    st[0] = v0.x; st[1] = v0.y; st[2] = v0.z; st[3] = v0.w;
    st[4] = v1.x; st[5] = v1.y; st[6] = v1.z; st[7] = v1.w;
    st[8] = v2.x; st[9] = v2.y; st[10] = v2.z; st[11] = v2.w;
    st[12] = v3.x; st[13] = v3.y; st[14] = v3.z; st[15] = v3.w;

    float h[H_DIM];
#pragma unroll
    for (int j = 0; j < H_DIM; ++j) {
        float acc = bout1[j];
#pragma unroll
        for (int k = 0; k < S_DIM; ++k) acc = fmaf(st[k], Wout1[(size_t)k * H_DIM + j], acc);
        h[j] = fast_tanh(acc);
    }
    float l[OUT_DIM];
#pragma unroll
    for (int i = 0; i < OUT_DIM; ++i) l[i] = bout2[i];
#pragma unroll
    for (int j = 0; j < H_DIM; ++j) {
        float hj = h[j];
#pragma unroll
        for (int i = 0; i < OUT_DIM; ++i) l[i] = fmaf(hj, Wout2[(size_t)j * OUT_DIM + i], l[i]);
    }
    float m = l[0];
#pragma unroll
    for (int i = 1; i < OUT_DIM; ++i) m = fmaxf(m, l[i]);
    float sum = 0.0f;
#pragma unroll
    for (int i = 0; i < OUT_DIM; ++i) {
        float tv = __expf(l[i] - m);
        l[i] = tv;
        sum += tv;
    }
    float inv = 1.0f / sum;
    float4* op = reinterpret_cast<float4*>(out + (size_t)n * OUT_DIM);
    op[0] = make_float4(l[0] * inv, l[1] * inv, l[2] * inv, l[3] * inv);
    op[1] = make_float4(l[4] * inv, l[5] * inv, l[6] * inv, l[7] * inv);
    op[2] = make_float4(l[8] * inv, l[9] * inv, l[10] * inv, l[11] * inv);
    op[3] = make_float4(l[12] * inv, l[13] * inv, l[14] * inv, l[15] * inv);
}

extern "C" void kernel_launch(void* const* d_in, const int* in_sizes, int n_in,
                              void* d_out, int out_size, void* d_ws, size_t ws_size,
                              hipStream_t stream) {
    const float* edge_feat = (const float*)d_in[0];
    const float* Wst1 = (const float*)d_in[1];
    const float* bst1 = (const float*)d_in[2];
    const float* Wst2 = (const float*)d_in[3];
    const float* bst2 = (const float*)d_in[4];
    const float* Wout1 = (const float*)d_in[5];
    const float* bout1 = (const float*)d_in[6];
    const float* Wout2 = (const float*)d_in[7];
    const float* bout2 = (const float*)d_in[8];
    const int* esrc = (const int*)d_in[9];
    const int* edst = (const int*)d_in[10];
    const int E = in_sizes[9];
    const int N = out_size / OUT_DIM;
    float* out = (float*)d_out;

    // ws layout (floats): state[N*16] | nodeH[N*32] | new_state[N*16] |
    // pre (_Float16, E*32) | pos[E] | dstp[E] | srcp[E] | deg[N] | cursor[N] | flags[8]
    float* state = (float*)d_ws;
    float* nodeH = state + (size_t)N * S_DIM;
    float* new_state = nodeH + (size_t)N * H_DIM;
    _Float16* pre = (_Float16*)(new_state + (size_t)N * S_DIM);
    int* pos = (int*)(pre + (size_t)E * H_DIM);
    int* dstp = pos + E;
    int* srcp = dstp + E;
    int* deg = srcp + E;
    int* cursor = deg + N;
    int* flags = cursor + N;

    hipMemsetAsync(state, 0, (size_t)N * (S_DIM + H_DIM + S_DIM) * sizeof(float), stream);
    hipMemsetAsync(deg, 0, (size_t)N * sizeof(int), stream);
    hipMemsetAsync(flags, 0, 8 * sizeof(int), stream);

    int ebl = (E + 255) / 256;
    int nbl = (N + 255) / 256;
    int rbl = (N * 4 + 255) / 256;

    k_hist<<<ebl, 256, 0, stream>>>(esrc, deg, E);
    k_scan<<<1, 1024, 0, stream>>>(deg, cursor, N);
    k_scatter<<<ebl, 256, 0, stream>>>(esrc, edst, cursor, pos, dstp, srcp, E);
    k_pre<<<ebl, 256, 0, stream>>>(edge_feat, Wst1, bst1, pos, pre, E);

    for (int it = 0; it < MAX_IT; ++it) {
        k_edge<<<ebl, 256, 0, stream>>>(pre, nodeH, dstp, srcp, Wst2, bst2,
                                        new_state, flags, it, E);
        k_node<<<rbl, 256, 0, stream>>>(state, new_state, nodeH, Wst1, flags, it, N);
    }
    gnn_out<<<nbl, 256, 0, stream>>>(state, Wout1, bout1, Wout2, bout2, out, N);
}